// Round 9
// baseline (1455.191 us; speedup 1.0000x reference)
//
#include <hip/hip_runtime.h>
#include <math.h>

#define B_ 8
#define NP_ 25600
#define T_ (B_*NP_)          // 204800 tokens
#define D_ 256
#define H_ 128
#define DD_ 128
#define NBINS_ 200
#define NIDS_ 400            // bin_idx in [0, 398]
#define PB_ 128              // bin size
#define NC_ 100              // codebook columns used
#define GT_ (B_*NBINS_)      // 1600 bins total

typedef __attribute__((ext_vector_type(8))) short bf16x8;
typedef __attribute__((ext_vector_type(4))) float f32x4;
typedef __attribute__((ext_vector_type(4))) unsigned short u16x4;
typedef unsigned short u16;

__device__ __forceinline__ float eluf(float v){ return v > 0.f ? v : expm1f(v); }
__device__ __forceinline__ u16 f2bf(float f){
  union { float f; unsigned u; } v; v.f = f;
  unsigned r = v.u + 0x7fffu + ((v.u >> 16) & 1u);
  return (u16)(r >> 16);
}
__device__ __forceinline__ float bf2f(u16 h){
  union { unsigned u; float f; } v; v.u = ((unsigned)h) << 16; return v.f;
}

// async global->LDS 16B (wave-uniform-ordered linear dest; per-lane global src)
__device__ __forceinline__ void gl16(void* lds, const void* g){
  __builtin_amdgcn_global_load_lds((const __attribute__((address_space(1))) void*)g,
                                   (__attribute__((address_space(3))) void*)lds, 16, 0, 0);
}

// ---------------- mask dtype detection & conversion ----------------
__global__ void k_mask_detect(const unsigned int* __restrict__ m, int* __restrict__ flags){
  int any_f1 = 0, any_o = 0;
  for (int i = blockIdx.x*blockDim.x + threadIdx.x; i < T_/4; i += gridDim.x*blockDim.x){
    unsigned int w = m[i];
    if (w == 0x3F800000u) any_f1 = 1;
    else if (w > 1u) any_o = 1;
  }
  if (any_f1) atomicOr(&flags[0], 1);
  if (any_o)  atomicOr(&flags[1], 1);
}

__global__ void k_mask_convert(const void* __restrict__ m, const int* __restrict__ flags,
                               float* __restrict__ mskf){
  int i = blockIdx.x*256 + threadIdx.x;
  int mode = flags[0] ? 2 : (flags[1] ? 1 : 0);  // 2=f32, 1=u8, 0=i32
  bool v;
  if (mode == 2)      v = ((const float*)m)[i] != 0.f;
  else if (mode == 1) v = ((const unsigned char*)m)[i] != 0;
  else                v = ((const int*)m)[i] != 0;
  mskf[i] = v ? 1.f : 0.f;
}

// ---------------- layernorm: one wave per token ----------------
__global__ __launch_bounds__(256) void k_ln(const float* __restrict__ x,
    const float* __restrict__ g, const float* __restrict__ b, float* __restrict__ xn){
  const int wave = threadIdx.x >> 6, lane = threadIdx.x & 63;
  const long t = (long)blockIdx.x*4 + wave;
  float4 v = ((const float4*)(x + t*D_))[lane];
  float s  = v.x + v.y + v.z + v.w;
  float s2 = v.x*v.x + v.y*v.y + v.z*v.z + v.w*v.w;
  #pragma unroll
  for (int o = 32; o; o >>= 1){ s += __shfl_xor(s, o); s2 += __shfl_xor(s2, o); }
  const float mu = s * (1.f/D_);
  float var = s2*(1.f/D_) - mu*mu;
  var = fmaxf(var, 0.f);
  const float rs = rsqrtf(var + 1e-6f);
  float4 gg = ((const float4*)g)[lane];
  float4 bb = ((const float4*)b)[lane];
  float4 o4;
  o4.x = (v.x-mu)*rs*gg.x + bb.x;
  o4.y = (v.y-mu)*rs*gg.y + bb.y;
  o4.z = (v.z-mu)*rs*gg.z + bb.z;
  o4.w = (v.w-mu)*rs*gg.w + bb.w;
  ((float4*)(xn + t*D_))[lane] = o4;
}

// ---------------- fp32 FFN GEMM: 128x128 tile, split microtile {t*4, 64+t*4} ----------------
template<int K>
__global__ __launch_bounds__(256) void k_gemm2(const float* __restrict__ A,
    const float* __restrict__ W, const float* __restrict__ bias, float* __restrict__ C){
  __shared__ __align__(16) float As[32*132];   // [k][m]
  __shared__ __align__(16) float Bs[32*132];   // [k][n]
  const size_t m0 = (size_t)blockIdx.x * 128;
  const int tid = threadIdx.x;
  const int tm = tid >> 4, tn = tid & 15;
  float acc[8][8] = {};
  for (int kc = 0; kc < K; kc += 32){
    __syncthreads();
    {
      const int r = tid >> 1, kq = (tid & 1) * 16;
      const float* src = &A[(m0 + r)*(size_t)K + kc + kq];
      #pragma unroll
      for (int q = 0; q < 4; ++q){
        const float4 v = ((const float4*)src)[q];
        As[(kq + q*4 + 0)*132 + r] = v.x;
        As[(kq + q*4 + 1)*132 + r] = v.y;
        As[(kq + q*4 + 2)*132 + r] = v.z;
        As[(kq + q*4 + 3)*132 + r] = v.w;
      }
      const int kk = tid >> 3, n0 = (tid & 7) * 16;
      const float* wsrc = &W[(size_t)(kc + kk)*128 + n0];
      #pragma unroll
      for (int q = 0; q < 4; ++q)
        *(float4*)&Bs[kk*132 + n0 + q*4] = ((const float4*)wsrc)[q];
    }
    __syncthreads();
    #pragma unroll
    for (int k = 0; k < 32; ++k){
      float a[8], b[8];
      *(float4*)&a[0] = *(const float4*)&As[k*132 + tm*4];
      *(float4*)&a[4] = *(const float4*)&As[k*132 + 64 + tm*4];
      *(float4*)&b[0] = *(const float4*)&Bs[k*132 + tn*4];
      *(float4*)&b[4] = *(const float4*)&Bs[k*132 + 64 + tn*4];
      #pragma unroll
      for (int i = 0; i < 8; ++i)
        #pragma unroll
        for (int j = 0; j < 8; ++j)
          acc[i][j] = fmaf(a[i], b[j], acc[i][j]);
    }
  }
  #pragma unroll
  for (int i = 0; i < 8; ++i){
    const size_t row = m0 + (i < 4 ? tm*4 + i : 64 + tm*4 + (i-4));
    #pragma unroll
    for (int q = 0; q < 2; ++q){
      const int c0 = q ? 64 + tn*4 : tn*4;
      float4 o;
      o.x = eluf(acc[i][q*4+0] + bias[c0+0]);
      o.y = eluf(acc[i][q*4+1] + bias[c0+1]);
      o.z = eluf(acc[i][q*4+2] + bias[c0+2]);
      o.w = eluf(acc[i][q*4+3] + bias[c0+3]);
      *(float4*)&C[row*128 + c0] = o;
    }
  }
}

// ---------------- codebook pad: cbp[128][128], cols >= 100 zero ----------------
__global__ void k_cbpad(const float* __restrict__ cb, float* __restrict__ cbp){
  const int k = blockIdx.x, c = threadIdx.x;   // 128 x 128
  cbp[k*128 + c] = (c < NC_) ? cb[k*NC_ + c] : 0.f;
}

// ---------------- fused mul GEMM + argmax (bins bit-identical; order-independent cmp) ----
__global__ __launch_bounds__(256) void k_mulmax(const float* __restrict__ A,
    const float* __restrict__ CB, const float* __restrict__ mskf, int* __restrict__ bidx){
  __shared__ __align__(16) float As[32*132];
  __shared__ __align__(16) float Bs[32*132];
  const size_t m0 = (size_t)blockIdx.x * 128;
  const int tid = threadIdx.x;
  const int tm = tid >> 4, tn = tid & 15;
  float acc[8][8] = {};
  for (int kc = 0; kc < DD_; kc += 32){
    __syncthreads();
    {
      const int r = tid >> 1, kq = (tid & 1) * 16;
      const float* src = &A[(m0 + r)*(size_t)DD_ + kc + kq];
      #pragma unroll
      for (int q = 0; q < 4; ++q){
        const float4 v = ((const float4*)src)[q];
        As[(kq + q*4 + 0)*132 + r] = v.x;
        As[(kq + q*4 + 1)*132 + r] = v.y;
        As[(kq + q*4 + 2)*132 + r] = v.z;
        As[(kq + q*4 + 3)*132 + r] = v.w;
      }
      const int kk = tid >> 3, n0 = (tid & 7) * 16;
      const float* wsrc = &CB[(size_t)(kc + kk)*128 + n0];
      #pragma unroll
      for (int q = 0; q < 4; ++q)
        *(float4*)&Bs[kk*132 + n0 + q*4] = ((const float4*)wsrc)[q];
    }
    __syncthreads();
    #pragma unroll
    for (int k = 0; k < 32; ++k){
      float a[8], b[8];
      *(float4*)&a[0] = *(const float4*)&As[k*132 + tm*4];
      *(float4*)&a[4] = *(const float4*)&As[k*132 + 64 + tm*4];
      *(float4*)&b[0] = *(const float4*)&Bs[k*132 + tn*4];
      *(float4*)&b[4] = *(const float4*)&Bs[k*132 + 64 + tn*4];
      #pragma unroll
      for (int i = 0; i < 8; ++i)
        #pragma unroll
        for (int j = 0; j < 8; ++j)
          acc[i][j] = fmaf(a[i], b[j], acc[i][j]);
    }
  }
  #pragma unroll
  for (int i = 0; i < 8; ++i){
    float bv = -1e30f; int bi = 0;
    #pragma unroll
    for (int j = 0; j < 8; ++j){
      const int c = (j < 4 ? tn*4 + j : 64 + tn*4 + (j-4));
      if (c < NC_){
        const float v = acc[i][j];
        if (v > bv || (v == bv && c < bi)){ bv = v; bi = c; }
        const float nv = -v; const int nc2 = c + NC_;
        if (nv > bv || (nv == bv && nc2 < bi)){ bv = nv; bi = nc2; }
      }
    }
    #pragma unroll
    for (int o = 1; o < 16; o <<= 1){
      const float ov = __shfl_xor(bv, o);
      const int oi = __shfl_xor(bi, o);
      if (ov > bv || (ov == bv && oi < bi)){ bv = ov; bi = oi; }
    }
    if (tn == 0){
      const size_t t = m0 + (i < 4 ? tm*4 + i : 64 + tm*4 + (i-4));
      bidx[t] = bi + (mskf[t] != 0.f ? 0 : NBINS_ - 1);
    }
  }
}

// ---------------- counting sort (stable) ----------------
__global__ void k_hist(const int* __restrict__ bidx, int* __restrict__ hist){
  const int i = blockIdx.x*256 + threadIdx.x;
  const int b = i / NP_;
  atomicAdd(&hist[b*NIDS_ + bidx[i]], 1);
}

__global__ void k_prefix(const int* __restrict__ hist, int* __restrict__ offs){
  const int b = threadIdx.x;
  if (b < B_){
    int run = 0;
    for (int v = 0; v < NIDS_; ++v){ offs[b*NIDS_ + v] = run; run += hist[b*NIDS_ + v]; }
  }
}

__global__ __launch_bounds__(64) void k_binsort(const int* __restrict__ bidx,
    const int* __restrict__ offs, const int* __restrict__ hist, int* __restrict__ split){
  const int bv = blockIdx.x;            // b*NIDS_ + v
  if (hist[bv] == 0) return;
  const int b = bv / NIDS_, v = bv % NIDS_;
  int base = offs[bv];
  const int lane = threadIdx.x;
  const int* row = bidx + b*NP_;
  for (int i0 = 0; i0 < NP_; i0 += 64){
    const int i = i0 + lane;
    const bool m = (row[i] == v);
    const unsigned long long mk = __ballot(m);
    if (m){
      const int pos = base + __popcll(mk & ((1ull << lane) - 1ull));
      split[b*NP_ + pos] = i;
    }
    base += __popcll(mk);
  }
}

// ---------------- gather (fp32 -> masked bf16), wave per token ----------------
__global__ __launch_bounds__(256) void k_gather(const float* __restrict__ xn,
    const float* __restrict__ xd, const float* __restrict__ mskf,
    const int* __restrict__ split, u16* __restrict__ xmh,
    u16* __restrict__ xkh, float* __restrict__ mskg){
  const long j = (long)blockIdx.x*4 + (threadIdx.x >> 6);
  const int lane = threadIdx.x & 63;
  const int b = (int)(j / NP_);
  const int i = split[j];
  const long src = (long)b*NP_ + i;
  const float mv = mskf[src];
  const float4 v = ((const float4*)(xn + src*D_))[lane];
  u16x4 o;
  o[0] = f2bf(v.x*mv); o[1] = f2bf(v.y*mv); o[2] = f2bf(v.z*mv); o[3] = f2bf(v.w*mv);
  ((u16x4*)(xmh + j*D_))[lane] = o;
  if (lane < 32){
    const float4 ww = ((const float4*)(xd + src*DD_))[lane];
    u16x4 ow;
    ow[0] = f2bf(ww.x*mv); ow[1] = f2bf(ww.y*mv); ow[2] = f2bf(ww.z*mv); ow[3] = f2bf(ww.w*mv);
    ((u16x4*)(xkh + j*DD_))[lane] = ow;
  }
  if (lane == 0) mskg[j] = mv;
}

// ---------------- weight prep ----------------
__global__ __launch_bounds__(256) void k_wt(const float* __restrict__ W, u16* __restrict__ o){
  const int n = blockIdx.x, k = threadIdx.x;
  o[n*D_ + k] = f2bf(W[k*D_ + n]);
}
__global__ __launch_bounds__(256) void k_wt2(const float* __restrict__ wt,
    const float* __restrict__ wh, u16* __restrict__ o){
  const int n = blockIdx.x, k = threadIdx.x;   // grid 512, thr 256
  const float v = (n < 256) ? wt[(size_t)k*D_ + n] : wh[(size_t)k*D_ + (n-256)];
  o[(size_t)n*D_ + k] = f2bf(v);
}

// ---------------- MFMA LDS staging via global_load_lds ----------------
__device__ __forceinline__ void stage64a(const u16* __restrict__ g, size_t row0,
    int ld, int k0, u16* Ls, int tid){
  const int w = tid >> 6, l = tid & 63;
  #pragma unroll
  for (int s = 0; s < 4; ++s){
    const int G = (s*4 + w)*64 + l;          // 0..1023; r = G>>3, c8 = G&7
    const int r = G >> 3, c8 = G & 7;
    gl16(&Ls[G*8], &g[(row0 + r)*(size_t)ld + k0 + ((c8 ^ (r & 7))*8)]);
  }
}
__device__ __forceinline__ void stage128a(const u16* __restrict__ g, size_t row0,
    int ld, u16* Ls, int tid){
  const int w = tid >> 6, l = tid & 63;
  #pragma unroll
  for (int s = 0; s < 8; ++s){
    const int G = (s*4 + w)*64 + l;          // 0..2047; r = G>>4, c8 = G&15
    const int r = G >> 4, c8 = G & 15;
    gl16(&Ls[G*8], &g[(row0 + r)*(size_t)ld + ((c8 ^ (r & 7))*8)]);
  }
}
__device__ __forceinline__ bf16x8 ldf(const u16* Ls, int row, int c8, int ldc8){
  return *(const bf16x8*)&Ls[(row*ldc8 + (c8 ^ (row & 7)))*8];
}

// ---------------- per-bin Gram + Gaussian kernel matrix (MFMA) ----------------
__global__ __launch_bounds__(256) void k_dm(const u16* __restrict__ xk,
    const float* __restrict__ rm, u16* __restrict__ dmb){
  __shared__ __align__(16) u16 Xs[128*128];
  __shared__ float nsq[128];
  __shared__ float msl[128];
  const int g = blockIdx.x;
  const int tid = threadIdx.x, l = tid & 63, wid = tid >> 6;
  const int wr = wid >> 1, wc = wid & 1, lm = l & 15, lk = l >> 4;
  stage128a(xk, (size_t)g*128, DD_, Xs, tid);
  if (tid < 128) msl[tid] = rm[(size_t)g*128 + tid];
  __syncthreads();
  f32x4 acc[4][4] = {};
  #pragma unroll
  for (int ks = 0; ks < 4; ++ks){
    bf16x8 a[4], b[4];
    #pragma unroll
    for (int mi = 0; mi < 4; ++mi) a[mi] = ldf(Xs, wr*64 + mi*16 + lm, ks*4 + lk, 16);
    #pragma unroll
    for (int ni = 0; ni < 4; ++ni) b[ni] = ldf(Xs, wc*64 + ni*16 + lm, ks*4 + lk, 16);
    #pragma unroll
    for (int mi = 0; mi < 4; ++mi)
      #pragma unroll
      for (int ni = 0; ni < 4; ++ni)
        acc[mi][ni] = __builtin_amdgcn_mfma_f32_16x16x32_bf16(a[mi], b[ni], acc[mi][ni], 0, 0, 0);
  }
  if (wr == wc && ((lm >> 2) == lk)){
    #pragma unroll
    for (int mi = 0; mi < 4; ++mi)
      nsq[wr*64 + mi*16 + lm] = acc[mi][mi][lm & 3];
  }
  __syncthreads();
  #pragma unroll
  for (int mi = 0; mi < 4; ++mi)
    #pragma unroll
    for (int ni = 0; ni < 4; ++ni)
      #pragma unroll
      for (int r = 0; r < 4; ++r){
        const int row = wr*64 + mi*16 + lk*4 + r;
        const int col = wc*64 + ni*16 + lm;
        float d2 = nsq[row] + nsq[col] - 2.f*acc[mi][ni][r];
        d2 = fminf(fmaxf(d2, 1e-6f), 1e6f);
        float w = expf(-0.1f * sqrtf(d2));
        w = fminf(w, 1.f);
        dmb[((size_t)g*PB_ + row)*PB_ + col] = f2bf(w * msl[row] * msl[col]);
      }
}

// ---------------- fully fused per-(h,g) kernel, single staging loop ----------------
// Merged loop per kt: stage {X, thT, wt, wh} (4x16KB) once; run all 3 GEMMs
// (a1 = thT@X^T; at = X@wt; ah = X@wh) — 96 MFMA per barrier window.
// Chains per accumulator remain kt-, ks-ascending with identical operands ->
// bit-identical to round 8. Epilogue stores via LDS for coalescing.
template<int OUT>
__global__ __launch_bounds__(256, 2) void k_fuse(const u16* __restrict__ dmb,
    const u16* __restrict__ thT, const u16* __restrict__ wtwh,
    const u16* __restrict__ X, const float* __restrict__ btv,
    const int* __restrict__ split, u16* __restrict__ o16, float* __restrict__ o32){
  __shared__ __align__(16) u16 smem[32768];     // 64KB
  __shared__ int ssp[128];
  u16* bufA = smem;            // loop: [0:8192]=X, [8192:16384]=thT; phase2: dm
  u16* bufB = smem + 16384;    // loop: [0:8192]=wt, [8192:16384]=wh; phase2: t^T
  const int bid = blockIdx.x;
  const int id = (bid & 7)*400 + (bid >> 3);    // XCD-swizzle: g-pairs share an XCD
  const int h = id & 1, g = id >> 1;
  const int tid = threadIdx.x, l = tid & 63, wid = tid >> 6;
  const int wr = wid >> 1, wc = wid & 1, lm = l & 15, lk = l >> 4;
  u16* stX = bufA;
  u16* stT = bufA + 8192;
  u16* stW = bufB;
  u16* stH = bufB + 8192;
  if (OUT){ if (tid < 128) ssp[tid] = split[g*128 + tid]; }
  f32x4 at[4][4] = {}, ah[4][4] = {}, a1[4][4] = {};
  for (int kt = 0; kt < 4; ++kt){
    __syncthreads();
    stage64a(X,    (size_t)g*128,       D_, kt*64, stX, tid);
    stage64a(thT,  (size_t)h*128,       D_, kt*64, stT, tid);
    stage64a(wtwh, (size_t)h*128,       D_, kt*64, stW, tid);
    stage64a(wtwh, (size_t)(256+h*128), D_, kt*64, stH, tid);
    __syncthreads();
    #pragma unroll
    for (int ks = 0; ks < 2; ++ks){
      // cluster 1: theta GEMM (thT rows as A, X rows as B)
      {
        bf16x8 ta[4], xb[4];
        #pragma unroll
        for (int mi = 0; mi < 4; ++mi) ta[mi] = ldf(stT, wr*64 + mi*16 + lm, ks*4 + lk, 8);
        #pragma unroll
        for (int ni = 0; ni < 4; ++ni) xb[ni] = ldf(stX, wc*64 + ni*16 + lm, ks*4 + lk, 8);
        #pragma unroll
        for (int mi = 0; mi < 4; ++mi)
          #pragma unroll
          for (int ni = 0; ni < 4; ++ni)
            a1[mi][ni] = __builtin_amdgcn_mfma_f32_16x16x32_bf16(ta[mi], xb[ni], a1[mi][ni], 0, 0, 0);
      }
      // cluster 2: gate GEMMs (X rows as A; wt/wh rows as B)
      {
        bf16x8 xa[4], wtf[4], whf[4];
        #pragma unroll
        for (int mi = 0; mi < 4; ++mi) xa[mi] = ldf(stX, wr*64 + mi*16 + lm, ks*4 + lk, 8);
        #pragma unroll
        for (int ni = 0; ni < 4; ++ni){
          wtf[ni] = ldf(stW, wc*64 + ni*16 + lm, ks*4 + lk, 8);
          whf[ni] = ldf(stH, wc*64 + ni*16 + lm, ks*4 + lk, 8);
        }
        #pragma unroll
        for (int mi = 0; mi < 4; ++mi)
          #pragma unroll
          for (int ni = 0; ni < 4; ++ni){
            at[mi][ni] = __builtin_amdgcn_mfma_f32_16x16x32_bf16(xa[mi], wtf[ni], at[mi][ni], 0, 0, 0);
            ah[mi][ni] = __builtin_amdgcn_mfma_f32_16x16x32_bf16(xa[mi], whf[ni], ah[mi][ni], 0, 0, 0);
          }
      }
    }
  }
  // pack gate logits to bf16 (matches old HBM round-trip exactly)
  u16x4 atp[4][4], ahp[4][4];
  #pragma unroll
  for (int mi = 0; mi < 4; ++mi)
    #pragma unroll
    for (int ni = 0; ni < 4; ++ni)
      #pragma unroll
      for (int r = 0; r < 4; ++r){
        atp[mi][ni][r] = f2bf(at[mi][ni][r]);
        ahp[mi][ni][r] = f2bf(ah[mi][ni][r]);
      }
  __syncthreads();
  // write t^T [n][p] into bufB (swizzled, ld 16 groups); stage dm into bufA
  #pragma unroll
  for (int mi = 0; mi < 4; ++mi)
    #pragma unroll
    for (int ni = 0; ni < 4; ++ni)
      #pragma unroll
      for (int r = 0; r < 4; ++r){
        const int row = wr*64 + mi*16 + lk*4 + r;   // n
        const int col = wc*64 + ni*16 + lm;         // p (= q of phase 2)
        bufB[(row*16 + ((col >> 3) ^ (row & 7)))*8 + (col & 7)] = f2bf(a1[mi][ni][r]);
      }
  stage128a(dmb, (size_t)g*128, PB_, bufA, tid);
  __syncthreads();
  // phase 2: fhom = dm @ t^T
  f32x4 acc[4][4] = {};
  #pragma unroll
  for (int ks = 0; ks < 4; ++ks){
    bf16x8 a[4], b[4];
    #pragma unroll
    for (int mi = 0; mi < 4; ++mi) a[mi] = ldf(bufA, wr*64 + mi*16 + lm, ks*4 + lk, 16);
    #pragma unroll
    for (int ni = 0; ni < 4; ++ni) b[ni] = ldf(bufB, wc*64 + ni*16 + lm, ks*4 + lk, 16);
    #pragma unroll
    for (int mi = 0; mi < 4; ++mi)
      #pragma unroll
      for (int ni = 0; ni < 4; ++ni)
        acc[mi][ni] = __builtin_amdgcn_mfma_f32_16x16x32_bf16(a[mi], b[ni], acc[mi][ni], 0, 0, 0);
  }
  __syncthreads();   // bufA/bufB reads done; reuse for epilogue staging
  // epilogue: gate/het mix -> LDS -> coalesced global stores
  if (OUT == 0){
    #pragma unroll
    for (int mi = 0; mi < 4; ++mi)
      #pragma unroll
      for (int ni = 0; ni < 4; ++ni){
        const int colc = wc*64 + ni*16 + lm;
        const float bb = btv[h*128 + colc];
        #pragma unroll
        for (int r = 0; r < 4; ++r){
          const int row = wr*64 + mi*16 + lk*4 + r;
          const float gt = 1.f/(1.f + expf(-(bf2f(atp[mi][ni][r]) + bb)));
          const float o = eluf(gt*acc[mi][ni][r] + (1.f - gt)*bf2f(ahp[mi][ni][r]));
          bufA[row*128 + colc] = f2bf(o);
        }
      }
    __syncthreads();
    #pragma unroll
    for (int s = 0; s < 8; ++s){
      const int G = s*256 + tid;
      const int r = G >> 4, c8 = G & 15;
      *(bf16x8*)&o16[((size_t)g*128 + r)*D_ + h*128 + c8*8] = *(const bf16x8*)&bufA[r*128 + c8*8];
    }
  } else {
    float* fb = (float*)smem;   // 128x128 f32 = 64KB
    #pragma unroll
    for (int mi = 0; mi < 4; ++mi)
      #pragma unroll
      for (int ni = 0; ni < 4; ++ni){
        const int colc = wc*64 + ni*16 + lm;
        const float bb = btv[h*128 + colc];
        #pragma unroll
        for (int r = 0; r < 4; ++r){
          const int row = wr*64 + mi*16 + lk*4 + r;
          const float gt = 1.f/(1.f + expf(-(bf2f(atp[mi][ni][r]) + bb)));
          fb[row*128 + colc] = eluf(gt*acc[mi][ni][r] + (1.f - gt)*bf2f(ahp[mi][ni][r]));
        }
      }
    __syncthreads();
    const int b = g / NBINS_;
    #pragma unroll
    for (int s = 0; s < 16; ++s){
      const int G = s*256 + tid;
      const int r = G >> 5, c4 = G & 31;
      const float4 v = *(const float4*)&fb[r*128 + c4*4];
      *(float4*)&o32[((size_t)b*NP_ + ssp[r])*D_ + h*128 + c4*4] = v;
    }
  }
}

// ---------------- driver ----------------
extern "C" void kernel_launch(void* const* d_in, const int* in_sizes, int n_in,
                              void* d_out, int out_size, void* d_ws, size_t ws_size,
                              hipStream_t stream){
  (void)in_sizes; (void)n_in; (void)out_size;
  const float* x    = (const float*)d_in[0];
  const void*  msk  = d_in[1];
  const float* ln_g = (const float*)d_in[2];
  const float* ln_b = (const float*)d_in[3];
  const float* w1 = (const float*)d_in[4];
  const float* b1 = (const float*)d_in[5];
  const float* w2 = (const float*)d_in[6];
  const float* b2 = (const float*)d_in[7];
  const float* w3 = (const float*)d_in[8];
  const float* b3 = (const float*)d_in[9];
  const float* cb = (const float*)d_in[10];
  const float* th0 = (const float*)d_in[11];
  const float* wh0 = (const float*)d_in[12];
  const float* wt0 = (const float*)d_in[13];
  const float* bt0 = (const float*)d_in[14];
  const float* th1 = (const float*)d_in[15];
  const float* wh1 = (const float*)d_in[16];
  const float* wt1 = (const float*)d_in[17];
  const float* bt1 = (const float*)d_in[18];
  float* out = (float*)d_out;

  char* ws = (char*)d_ws;
  size_t off = 0;
  auto alloc = [&](size_t bytes) -> void* {
    void* p = ws + off; off += (bytes + 255) & ~(size_t)255; return p;
  };
  int* flags = (int*)alloc(2*sizeof(int));
  int* hist  = (int*)alloc((size_t)B_*NIDS_*4);
  int* offs  = (int*)alloc((size_t)B_*NIDS_*4);
  int* bidx  = (int*)alloc((size_t)T_*4);
  int* split = (int*)alloc((size_t)T_*4);
  float* mskf = (float*)alloc((size_t)T_*4);
  float* mskg = (float*)alloc((size_t)T_*4);
  float* cbp = (float*)alloc((size_t)128*128*4);
  u16* thT0 = (u16*)alloc((size_t)D_*D_*2);
  u16* thT1 = (u16*)alloc((size_t)D_*D_*2);
  u16* wtwh0 = (u16*)alloc((size_t)512*D_*2);
  u16* wtwh1 = (u16*)alloc((size_t)512*D_*2);
  // BIG0: FFN intermediates P|Q (fp32, T*128 each)
  char* regA = (char*)alloc((size_t)T_*512*2);
  // BIG1..BIG3
  u16* xmh = (u16*)alloc((size_t)T_*D_*2);
  char* regC = (char*)alloc((size_t)T_*D_*2);   // xkh | dmb
  u16* xb1 = (u16*)alloc((size_t)T_*D_*2);
  if (off > ws_size) return;  // insufficient workspace: leave poison (visible failure)

  float* P = (float*)regA;
  float* Q = P + (size_t)T_*DD_;
  u16* xkh = (u16*)regC;
  u16* dmb = xkh + (size_t)T_*DD_;
  float* xn = out;            // d_out holds xn until the final k_fuse<1> scatter

  hipMemsetAsync(flags, 0, 2*sizeof(int), stream);
  hipMemsetAsync(hist, 0, (size_t)B_*NIDS_*4, stream);

  k_mask_detect<<<64, 256, 0, stream>>>((const unsigned int*)msk, flags);
  k_mask_convert<<<T_/256, 256, 0, stream>>>(msk, flags, mskf);

  k_ln<<<T_/4, 256, 0, stream>>>(x, ln_g, ln_b, xn);

  k_cbpad<<<128, 128, 0, stream>>>(cb, cbp);
  k_wt<<<256, 256, 0, stream>>>(th0, thT0);
  k_wt<<<256, 256, 0, stream>>>(th1, thT1);
  k_wt2<<<512, 256, 0, stream>>>(wt0, wh0, wtwh0);
  k_wt2<<<512, 256, 0, stream>>>(wt1, wh1, wtwh1);

  // FFN (exact fp32 — same per-output fmaf chains; bins bit-identical)
  k_gemm2<D_><<<T_/128, 256, 0, stream>>>(xn, w1, b1, P);
  k_gemm2<H_><<<T_/128, 256, 0, stream>>>(P, w2, b2, Q);
  k_gemm2<H_><<<T_/128, 256, 0, stream>>>(Q, w3, b3, P);

  // LSH
  k_mulmax<<<T_/128, 256, 0, stream>>>(P, cbp, mskf, bidx);
  k_hist<<<T_/256, 256, 0, stream>>>(bidx, hist);
  k_prefix<<<1, 64, 0, stream>>>(hist, offs);
  k_binsort<<<B_*NIDS_, 64, 0, stream>>>(bidx, offs, hist, split);

  k_gather<<<T_/4, 256, 0, stream>>>(xn, P, mskf, split, xmh, xkh, mskg);
  k_dm<<<GT_, 256, 0, stream>>>(xkh, mskg, dmb);

  // layer 0 (fully fused, merged staging loop; 1D grid with XCD swizzle)
  k_fuse<0><<<2*GT_, 256, 0, stream>>>(dmb, thT0, wtwh0, xmh, bt0, nullptr, xb1, nullptr);
  // layer 1 (writes final output scattered via split)
  k_fuse<1><<<2*GT_, 256, 0, stream>>>(dmb, thT1, wtwh1, xb1, bt1, split, nullptr, out);
}

// Round 10
// 1279.811 us; speedup vs baseline: 1.1370x; 1.1370x over previous
//
#include <hip/hip_runtime.h>
#include <math.h>

#define B_ 8
#define NP_ 25600
#define T_ (B_*NP_)          // 204800 tokens
#define D_ 256
#define H_ 128
#define DD_ 128
#define NBINS_ 200
#define NIDS_ 400            // bin_idx in [0, 398]
#define PB_ 128              // bin size
#define NC_ 100              // codebook columns used
#define GT_ (B_*NBINS_)      // 1600 bins total

typedef __attribute__((ext_vector_type(8))) short bf16x8;
typedef __attribute__((ext_vector_type(4))) float f32x4;
typedef __attribute__((ext_vector_type(4))) unsigned short u16x4;
typedef unsigned short u16;

__device__ __forceinline__ float eluf(float v){ return v > 0.f ? v : expm1f(v); }
__device__ __forceinline__ u16 f2bf(float f){
  union { float f; unsigned u; } v; v.f = f;
  unsigned r = v.u + 0x7fffu + ((v.u >> 16) & 1u);
  return (u16)(r >> 16);
}
__device__ __forceinline__ float bf2f(u16 h){
  union { unsigned u; float f; } v; v.u = ((unsigned)h) << 16; return v.f;
}

// async global->LDS 16B (wave-uniform-ordered linear dest; per-lane global src)
__device__ __forceinline__ void gl16(void* lds, const void* g){
  __builtin_amdgcn_global_load_lds((const __attribute__((address_space(1))) void*)g,
                                   (__attribute__((address_space(3))) void*)lds, 16, 0, 0);
}

// ---------------- mask dtype detection & conversion ----------------
__global__ void k_mask_detect(const unsigned int* __restrict__ m, int* __restrict__ flags){
  int any_f1 = 0, any_o = 0;
  for (int i = blockIdx.x*blockDim.x + threadIdx.x; i < T_/4; i += gridDim.x*blockDim.x){
    unsigned int w = m[i];
    if (w == 0x3F800000u) any_f1 = 1;
    else if (w > 1u) any_o = 1;
  }
  if (any_f1) atomicOr(&flags[0], 1);
  if (any_o)  atomicOr(&flags[1], 1);
}

__global__ void k_mask_convert(const void* __restrict__ m, const int* __restrict__ flags,
                               float* __restrict__ mskf){
  int i = blockIdx.x*256 + threadIdx.x;
  int mode = flags[0] ? 2 : (flags[1] ? 1 : 0);  // 2=f32, 1=u8, 0=i32
  bool v;
  if (mode == 2)      v = ((const float*)m)[i] != 0.f;
  else if (mode == 1) v = ((const unsigned char*)m)[i] != 0;
  else                v = ((const int*)m)[i] != 0;
  mskf[i] = v ? 1.f : 0.f;
}

// ---------------- layernorm: one wave per token ----------------
__global__ __launch_bounds__(256) void k_ln(const float* __restrict__ x,
    const float* __restrict__ g, const float* __restrict__ b, float* __restrict__ xn){
  const int wave = threadIdx.x >> 6, lane = threadIdx.x & 63;
  const long t = (long)blockIdx.x*4 + wave;
  float4 v = ((const float4*)(x + t*D_))[lane];
  float s  = v.x + v.y + v.z + v.w;
  float s2 = v.x*v.x + v.y*v.y + v.z*v.z + v.w*v.w;
  #pragma unroll
  for (int o = 32; o; o >>= 1){ s += __shfl_xor(s, o); s2 += __shfl_xor(s2, o); }
  const float mu = s * (1.f/D_);
  float var = s2*(1.f/D_) - mu*mu;
  var = fmaxf(var, 0.f);
  const float rs = rsqrtf(var + 1e-6f);
  float4 gg = ((const float4*)g)[lane];
  float4 bb = ((const float4*)b)[lane];
  float4 o4;
  o4.x = (v.x-mu)*rs*gg.x + bb.x;
  o4.y = (v.y-mu)*rs*gg.y + bb.y;
  o4.z = (v.z-mu)*rs*gg.z + bb.z;
  o4.w = (v.w-mu)*rs*gg.w + bb.w;
  ((float4*)(xn + t*D_))[lane] = o4;
}

// ---------------- fp32 FFN GEMM: 128x128 tile, split microtile {t*4, 64+t*4} ----------------
template<int K>
__global__ __launch_bounds__(256) void k_gemm2(const float* __restrict__ A,
    const float* __restrict__ W, const float* __restrict__ bias, float* __restrict__ C){
  __shared__ __align__(16) float As[32*132];   // [k][m]
  __shared__ __align__(16) float Bs[32*132];   // [k][n]
  const size_t m0 = (size_t)blockIdx.x * 128;
  const int tid = threadIdx.x;
  const int tm = tid >> 4, tn = tid & 15;
  float acc[8][8] = {};
  for (int kc = 0; kc < K; kc += 32){
    __syncthreads();
    {
      const int r = tid >> 1, kq = (tid & 1) * 16;
      const float* src = &A[(m0 + r)*(size_t)K + kc + kq];
      #pragma unroll
      for (int q = 0; q < 4; ++q){
        const float4 v = ((const float4*)src)[q];
        As[(kq + q*4 + 0)*132 + r] = v.x;
        As[(kq + q*4 + 1)*132 + r] = v.y;
        As[(kq + q*4 + 2)*132 + r] = v.z;
        As[(kq + q*4 + 3)*132 + r] = v.w;
      }
      const int kk = tid >> 3, n0 = (tid & 7) * 16;
      const float* wsrc = &W[(size_t)(kc + kk)*128 + n0];
      #pragma unroll
      for (int q = 0; q < 4; ++q)
        *(float4*)&Bs[kk*132 + n0 + q*4] = ((const float4*)wsrc)[q];
    }
    __syncthreads();
    #pragma unroll
    for (int k = 0; k < 32; ++k){
      float a[8], b[8];
      *(float4*)&a[0] = *(const float4*)&As[k*132 + tm*4];
      *(float4*)&a[4] = *(const float4*)&As[k*132 + 64 + tm*4];
      *(float4*)&b[0] = *(const float4*)&Bs[k*132 + tn*4];
      *(float4*)&b[4] = *(const float4*)&Bs[k*132 + 64 + tn*4];
      #pragma unroll
      for (int i = 0; i < 8; ++i)
        #pragma unroll
        for (int j = 0; j < 8; ++j)
          acc[i][j] = fmaf(a[i], b[j], acc[i][j]);
    }
  }
  #pragma unroll
  for (int i = 0; i < 8; ++i){
    const size_t row = m0 + (i < 4 ? tm*4 + i : 64 + tm*4 + (i-4));
    #pragma unroll
    for (int q = 0; q < 2; ++q){
      const int c0 = q ? 64 + tn*4 : tn*4;
      float4 o;
      o.x = eluf(acc[i][q*4+0] + bias[c0+0]);
      o.y = eluf(acc[i][q*4+1] + bias[c0+1]);
      o.z = eluf(acc[i][q*4+2] + bias[c0+2]);
      o.w = eluf(acc[i][q*4+3] + bias[c0+3]);
      *(float4*)&C[row*128 + c0] = o;
    }
  }
}

// ---------------- codebook pad: cbp[128][128], cols >= 100 zero ----------------
__global__ void k_cbpad(const float* __restrict__ cb, float* __restrict__ cbp){
  const int k = blockIdx.x, c = threadIdx.x;   // 128 x 128
  cbp[k*128 + c] = (c < NC_) ? cb[k*NC_ + c] : 0.f;
}

// ---------------- fused mul GEMM + argmax (bins bit-identical; order-independent cmp) ----
__global__ __launch_bounds__(256) void k_mulmax(const float* __restrict__ A,
    const float* __restrict__ CB, const float* __restrict__ mskf, int* __restrict__ bidx){
  __shared__ __align__(16) float As[32*132];
  __shared__ __align__(16) float Bs[32*132];
  const size_t m0 = (size_t)blockIdx.x * 128;
  const int tid = threadIdx.x;
  const int tm = tid >> 4, tn = tid & 15;
  float acc[8][8] = {};
  for (int kc = 0; kc < DD_; kc += 32){
    __syncthreads();
    {
      const int r = tid >> 1, kq = (tid & 1) * 16;
      const float* src = &A[(m0 + r)*(size_t)DD_ + kc + kq];
      #pragma unroll
      for (int q = 0; q < 4; ++q){
        const float4 v = ((const float4*)src)[q];
        As[(kq + q*4 + 0)*132 + r] = v.x;
        As[(kq + q*4 + 1)*132 + r] = v.y;
        As[(kq + q*4 + 2)*132 + r] = v.z;
        As[(kq + q*4 + 3)*132 + r] = v.w;
      }
      const int kk = tid >> 3, n0 = (tid & 7) * 16;
      const float* wsrc = &CB[(size_t)(kc + kk)*128 + n0];
      #pragma unroll
      for (int q = 0; q < 4; ++q)
        *(float4*)&Bs[kk*132 + n0 + q*4] = ((const float4*)wsrc)[q];
    }
    __syncthreads();
    #pragma unroll
    for (int k = 0; k < 32; ++k){
      float a[8], b[8];
      *(float4*)&a[0] = *(const float4*)&As[k*132 + tm*4];
      *(float4*)&a[4] = *(const float4*)&As[k*132 + 64 + tm*4];
      *(float4*)&b[0] = *(const float4*)&Bs[k*132 + tn*4];
      *(float4*)&b[4] = *(const float4*)&Bs[k*132 + 64 + tn*4];
      #pragma unroll
      for (int i = 0; i < 8; ++i)
        #pragma unroll
        for (int j = 0; j < 8; ++j)
          acc[i][j] = fmaf(a[i], b[j], acc[i][j]);
    }
  }
  #pragma unroll
  for (int i = 0; i < 8; ++i){
    float bv = -1e30f; int bi = 0;
    #pragma unroll
    for (int j = 0; j < 8; ++j){
      const int c = (j < 4 ? tn*4 + j : 64 + tn*4 + (j-4));
      if (c < NC_){
        const float v = acc[i][j];
        if (v > bv || (v == bv && c < bi)){ bv = v; bi = c; }
        const float nv = -v; const int nc2 = c + NC_;
        if (nv > bv || (nv == bv && nc2 < bi)){ bv = nv; bi = nc2; }
      }
    }
    #pragma unroll
    for (int o = 1; o < 16; o <<= 1){
      const float ov = __shfl_xor(bv, o);
      const int oi = __shfl_xor(bi, o);
      if (ov > bv || (ov == bv && oi < bi)){ bv = ov; bi = oi; }
    }
    if (tn == 0){
      const size_t t = m0 + (i < 4 ? tm*4 + i : 64 + tm*4 + (i-4));
      bidx[t] = bi + (mskf[t] != 0.f ? 0 : NBINS_ - 1);
    }
  }
}

// ---------------- counting sort (stable) ----------------
__global__ void k_hist(const int* __restrict__ bidx, int* __restrict__ hist){
  const int i = blockIdx.x*256 + threadIdx.x;
  const int b = i / NP_;
  atomicAdd(&hist[b*NIDS_ + bidx[i]], 1);
}

__global__ void k_prefix(const int* __restrict__ hist, int* __restrict__ offs){
  const int b = threadIdx.x;
  if (b < B_){
    int run = 0;
    for (int v = 0; v < NIDS_; ++v){ offs[b*NIDS_ + v] = run; run += hist[b*NIDS_ + v]; }
  }
}

__global__ __launch_bounds__(64) void k_binsort(const int* __restrict__ bidx,
    const int* __restrict__ offs, const int* __restrict__ hist, int* __restrict__ split){
  const int bv = blockIdx.x;            // b*NIDS_ + v
  if (hist[bv] == 0) return;
  const int b = bv / NIDS_, v = bv % NIDS_;
  int base = offs[bv];
  const int lane = threadIdx.x;
  const int* row = bidx + b*NP_;
  for (int i0 = 0; i0 < NP_; i0 += 64){
    const int i = i0 + lane;
    const bool m = (row[i] == v);
    const unsigned long long mk = __ballot(m);
    if (m){
      const int pos = base + __popcll(mk & ((1ull << lane) - 1ull));
      split[b*NP_ + pos] = i;
    }
    base += __popcll(mk);
  }
}

// ---------------- gather (fp32 -> masked bf16), wave per token ----------------
__global__ __launch_bounds__(256) void k_gather(const float* __restrict__ xn,
    const float* __restrict__ xd, const float* __restrict__ mskf,
    const int* __restrict__ split, u16* __restrict__ xmh,
    u16* __restrict__ xkh, float* __restrict__ mskg){
  const long j = (long)blockIdx.x*4 + (threadIdx.x >> 6);
  const int lane = threadIdx.x & 63;
  const int b = (int)(j / NP_);
  const int i = split[j];
  const long src = (long)b*NP_ + i;
  const float mv = mskf[src];
  const float4 v = ((const float4*)(xn + src*D_))[lane];
  u16x4 o;
  o[0] = f2bf(v.x*mv); o[1] = f2bf(v.y*mv); o[2] = f2bf(v.z*mv); o[3] = f2bf(v.w*mv);
  ((u16x4*)(xmh + j*D_))[lane] = o;
  if (lane < 32){
    const float4 ww = ((const float4*)(xd + src*DD_))[lane];
    u16x4 ow;
    ow[0] = f2bf(ww.x*mv); ow[1] = f2bf(ww.y*mv); ow[2] = f2bf(ww.z*mv); ow[3] = f2bf(ww.w*mv);
    ((u16x4*)(xkh + j*DD_))[lane] = ow;
  }
  if (lane == 0) mskg[j] = mv;
}

// ---------------- weight prep ----------------
__global__ __launch_bounds__(256) void k_wt(const float* __restrict__ W, u16* __restrict__ o){
  const int n = blockIdx.x, k = threadIdx.x;
  o[n*D_ + k] = f2bf(W[k*D_ + n]);
}
__global__ __launch_bounds__(256) void k_wt2(const float* __restrict__ wt,
    const float* __restrict__ wh, u16* __restrict__ o){
  const int n = blockIdx.x, k = threadIdx.x;   // grid 512, thr 256
  const float v = (n < 256) ? wt[(size_t)k*D_ + n] : wh[(size_t)k*D_ + (n-256)];
  o[(size_t)n*D_ + k] = f2bf(v);
}

// ---------------- MFMA LDS staging via global_load_lds ----------------
__device__ __forceinline__ void stage64a(const u16* __restrict__ g, size_t row0,
    int ld, int k0, u16* Ls, int tid){
  const int w = tid >> 6, l = tid & 63;
  #pragma unroll
  for (int s = 0; s < 4; ++s){
    const int G = (s*4 + w)*64 + l;          // 0..1023; r = G>>3, c8 = G&7
    const int r = G >> 3, c8 = G & 7;
    gl16(&Ls[G*8], &g[(row0 + r)*(size_t)ld + k0 + ((c8 ^ (r & 7))*8)]);
  }
}
__device__ __forceinline__ void stage128a(const u16* __restrict__ g, size_t row0,
    int ld, u16* Ls, int tid){
  const int w = tid >> 6, l = tid & 63;
  #pragma unroll
  for (int s = 0; s < 8; ++s){
    const int G = (s*4 + w)*64 + l;          // 0..2047; r = G>>4, c8 = G&15
    const int r = G >> 4, c8 = G & 15;
    gl16(&Ls[G*8], &g[(row0 + r)*(size_t)ld + ((c8 ^ (r & 7))*8)]);
  }
}
__device__ __forceinline__ bf16x8 ldf(const u16* Ls, int row, int c8, int ldc8){
  return *(const bf16x8*)&Ls[(row*ldc8 + (c8 ^ (row & 7)))*8];
}

// ---------------- per-bin Gram + Gaussian kernel matrix (MFMA) ----------------
__global__ __launch_bounds__(256) void k_dm(const u16* __restrict__ xk,
    const float* __restrict__ rm, u16* __restrict__ dmb){
  __shared__ __align__(16) u16 Xs[128*128];
  __shared__ float nsq[128];
  __shared__ float msl[128];
  const int g = blockIdx.x;
  const int tid = threadIdx.x, l = tid & 63, wid = tid >> 6;
  const int wr = wid >> 1, wc = wid & 1, lm = l & 15, lk = l >> 4;
  stage128a(xk, (size_t)g*128, DD_, Xs, tid);
  if (tid < 128) msl[tid] = rm[(size_t)g*128 + tid];
  __syncthreads();
  f32x4 acc[4][4] = {};
  #pragma unroll
  for (int ks = 0; ks < 4; ++ks){
    bf16x8 a[4], b[4];
    #pragma unroll
    for (int mi = 0; mi < 4; ++mi) a[mi] = ldf(Xs, wr*64 + mi*16 + lm, ks*4 + lk, 16);
    #pragma unroll
    for (int ni = 0; ni < 4; ++ni) b[ni] = ldf(Xs, wc*64 + ni*16 + lm, ks*4 + lk, 16);
    #pragma unroll
    for (int mi = 0; mi < 4; ++mi)
      #pragma unroll
      for (int ni = 0; ni < 4; ++ni)
        acc[mi][ni] = __builtin_amdgcn_mfma_f32_16x16x32_bf16(a[mi], b[ni], acc[mi][ni], 0, 0, 0);
  }
  if (wr == wc && ((lm >> 2) == lk)){
    #pragma unroll
    for (int mi = 0; mi < 4; ++mi)
      nsq[wr*64 + mi*16 + lm] = acc[mi][mi][lm & 3];
  }
  __syncthreads();
  #pragma unroll
  for (int mi = 0; mi < 4; ++mi)
    #pragma unroll
    for (int ni = 0; ni < 4; ++ni)
      #pragma unroll
      for (int r = 0; r < 4; ++r){
        const int row = wr*64 + mi*16 + lk*4 + r;
        const int col = wc*64 + ni*16 + lm;
        float d2 = nsq[row] + nsq[col] - 2.f*acc[mi][ni][r];
        d2 = fminf(fmaxf(d2, 1e-6f), 1e6f);
        float w = expf(-0.1f * sqrtf(d2));
        w = fminf(w, 1.f);
        dmb[((size_t)g*PB_ + row)*PB_ + col] = f2bf(w * msl[row] * msl[col]);
      }
}

// ---------------- fully fused per-(h,g) kernel (round-8 two-phase schedule) ----------------
// Loop AB: at/ah = X @ {wt,wh}  (2 acc sets live) -> pack to bf16 (frees 128 regs)
// Loop C:  a1 = thT @ X^T       (1 acc set + packed gates)
// Phase 2: fhom = dm @ t^T; epilogue via LDS for coalesced stores.
// 1D grid with XCD swizzle: g-pairs and 200 consecutive g per XCD (L2 sharing).
// Bit-identical math to rounds 7/8/9.
template<int OUT>
__global__ __launch_bounds__(256, 2) void k_fuse(const u16* __restrict__ dmb,
    const u16* __restrict__ thT, const u16* __restrict__ wtwh,
    const u16* __restrict__ X, const float* __restrict__ btv,
    const int* __restrict__ split, u16* __restrict__ o16, float* __restrict__ o32){
  __shared__ __align__(16) u16 smem[32768];     // 64KB
  __shared__ int ssp[128];
  u16* bufA = smem;
  u16* bufB = smem + 16384;
  const int bid = blockIdx.x;
  const int id = (bid & 7)*400 + (bid >> 3);    // XCD-swizzle (3200 % 8 == 0, bijective)
  const int h = id & 1, g = id >> 1;
  const int tid = threadIdx.x, l = tid & 63, wid = tid >> 6;
  const int wr = wid >> 1, wc = wid & 1, lm = l & 15, lk = l >> 4;
  u16* SBw = bufB;              // wt stage (16KB)
  u16* SBh = bufB + 8192;       // wh stage (16KB)
  if (OUT){ if (tid < 128) ssp[tid] = split[g*128 + tid]; }
  // ---- loop AB: gate GEMMs (at, ah), X as A-operand ----
  f32x4 at[4][4] = {}, ah[4][4] = {};
  for (int kt = 0; kt < 4; ++kt){
    __syncthreads();
    stage64a(X,    (size_t)g*128,       D_, kt*64, bufA, tid);
    stage64a(wtwh, (size_t)h*128,       D_, kt*64, SBw, tid);
    stage64a(wtwh, (size_t)(256+h*128), D_, kt*64, SBh, tid);
    __syncthreads();
    #pragma unroll
    for (int ks = 0; ks < 2; ++ks){
      bf16x8 xa[4], bt_[4], bh_[4];
      #pragma unroll
      for (int mi = 0; mi < 4; ++mi) xa[mi] = ldf(bufA, wr*64 + mi*16 + lm, ks*4 + lk, 8);
      #pragma unroll
      for (int ni = 0; ni < 4; ++ni){
        bt_[ni] = ldf(SBw, wc*64 + ni*16 + lm, ks*4 + lk, 8);
        bh_[ni] = ldf(SBh, wc*64 + ni*16 + lm, ks*4 + lk, 8);
      }
      #pragma unroll
      for (int mi = 0; mi < 4; ++mi)
        #pragma unroll
        for (int ni = 0; ni < 4; ++ni){
          at[mi][ni] = __builtin_amdgcn_mfma_f32_16x16x32_bf16(xa[mi], bt_[ni], at[mi][ni], 0, 0, 0);
          ah[mi][ni] = __builtin_amdgcn_mfma_f32_16x16x32_bf16(xa[mi], bh_[ni], ah[mi][ni], 0, 0, 0);
        }
    }
  }
  // pack gate logits to bf16 (matches old HBM round-trip exactly; frees acc regs)
  u16x4 atp[4][4], ahp[4][4];
  #pragma unroll
  for (int mi = 0; mi < 4; ++mi)
    #pragma unroll
    for (int ni = 0; ni < 4; ++ni)
      #pragma unroll
      for (int r = 0; r < 4; ++r){
        atp[mi][ni][r] = f2bf(at[mi][ni][r]);
        ahp[mi][ni][r] = f2bf(ah[mi][ni][r]);
      }
  // ---- loop C: theta GEMM (thT as A-operand, X as B-operand) ----
  f32x4 a1[4][4] = {};
  for (int kt = 0; kt < 4; ++kt){
    __syncthreads();
    stage64a(thT, (size_t)h*128, D_, kt*64, bufA, tid);
    stage64a(X,   (size_t)g*128, D_, kt*64, bufB, tid);
    __syncthreads();
    #pragma unroll
    for (int ks = 0; ks < 2; ++ks){
      bf16x8 a[4], b[4];
      #pragma unroll
      for (int mi = 0; mi < 4; ++mi) a[mi] = ldf(bufA, wr*64 + mi*16 + lm, ks*4 + lk, 8);
      #pragma unroll
      for (int ni = 0; ni < 4; ++ni) b[ni] = ldf(bufB, wc*64 + ni*16 + lm, ks*4 + lk, 8);
      #pragma unroll
      for (int mi = 0; mi < 4; ++mi)
        #pragma unroll
        for (int ni = 0; ni < 4; ++ni)
          a1[mi][ni] = __builtin_amdgcn_mfma_f32_16x16x32_bf16(a[mi], b[ni], a1[mi][ni], 0, 0, 0);
    }
  }
  __syncthreads();
  // ---- write t^T [n][p] into bufB (swizzled); stage dm into bufA ----
  #pragma unroll
  for (int mi = 0; mi < 4; ++mi)
    #pragma unroll
    for (int ni = 0; ni < 4; ++ni)
      #pragma unroll
      for (int r = 0; r < 4; ++r){
        const int row = wr*64 + mi*16 + lk*4 + r;   // n
        const int col = wc*64 + ni*16 + lm;         // p (= q of phase 2)
        bufB[(row*16 + ((col >> 3) ^ (row & 7)))*8 + (col & 7)] = f2bf(a1[mi][ni][r]);
      }
  stage128a(dmb, (size_t)g*128, PB_, bufA, tid);
  __syncthreads();
  // ---- phase 2: fhom = dm @ t^T ----
  f32x4 acc[4][4] = {};
  #pragma unroll
  for (int ks = 0; ks < 4; ++ks){
    bf16x8 a[4], b[4];
    #pragma unroll
    for (int mi = 0; mi < 4; ++mi) a[mi] = ldf(bufA, wr*64 + mi*16 + lm, ks*4 + lk, 16);
    #pragma unroll
    for (int ni = 0; ni < 4; ++ni) b[ni] = ldf(bufB, wc*64 + ni*16 + lm, ks*4 + lk, 16);
    #pragma unroll
    for (int mi = 0; mi < 4; ++mi)
      #pragma unroll
      for (int ni = 0; ni < 4; ++ni)
        acc[mi][ni] = __builtin_amdgcn_mfma_f32_16x16x32_bf16(a[mi], b[ni], acc[mi][ni], 0, 0, 0);
  }
  __syncthreads();   // bufA/bufB reads done; reuse for epilogue staging
  // ---- epilogue: gate/het mix -> LDS -> coalesced global stores ----
  if (OUT == 0){
    #pragma unroll
    for (int mi = 0; mi < 4; ++mi)
      #pragma unroll
      for (int ni = 0; ni < 4; ++ni){
        const int colc = wc*64 + ni*16 + lm;
        const float bb = btv[h*128 + colc];
        #pragma unroll
        for (int r = 0; r < 4; ++r){
          const int row = wr*64 + mi*16 + lk*4 + r;
          const float gt = 1.f/(1.f + expf(-(bf2f(atp[mi][ni][r]) + bb)));
          const float o = eluf(gt*acc[mi][ni][r] + (1.f - gt)*bf2f(ahp[mi][ni][r]));
          bufA[row*128 + colc] = f2bf(o);
        }
      }
    __syncthreads();
    #pragma unroll
    for (int s = 0; s < 8; ++s){
      const int G = s*256 + tid;
      const int r = G >> 4, c8 = G & 15;
      *(bf16x8*)&o16[((size_t)g*128 + r)*D_ + h*128 + c8*8] = *(const bf16x8*)&bufA[r*128 + c8*8];
    }
  } else {
    float* fb = (float*)smem;   // 128x128 f32 = 64KB
    #pragma unroll
    for (int mi = 0; mi < 4; ++mi)
      #pragma unroll
      for (int ni = 0; ni < 4; ++ni){
        const int colc = wc*64 + ni*16 + lm;
        const float bb = btv[h*128 + colc];
        #pragma unroll
        for (int r = 0; r < 4; ++r){
          const int row = wr*64 + mi*16 + lk*4 + r;
          const float gt = 1.f/(1.f + expf(-(bf2f(atp[mi][ni][r]) + bb)));
          fb[row*128 + colc] = eluf(gt*acc[mi][ni][r] + (1.f - gt)*bf2f(ahp[mi][ni][r]));
        }
      }
    __syncthreads();
    const int b = g / NBINS_;
    #pragma unroll
    for (int s = 0; s < 16; ++s){
      const int G = s*256 + tid;
      const int r = G >> 5, c4 = G & 31;
      const float4 v = *(const float4*)&fb[r*128 + c4*4];
      *(float4*)&o32[((size_t)b*NP_ + ssp[r])*D_ + h*128 + c4*4] = v;
    }
  }
}

// ---------------- driver ----------------
extern "C" void kernel_launch(void* const* d_in, const int* in_sizes, int n_in,
                              void* d_out, int out_size, void* d_ws, size_t ws_size,
                              hipStream_t stream){
  (void)in_sizes; (void)n_in; (void)out_size;
  const float* x    = (const float*)d_in[0];
  const void*  msk  = d_in[1];
  const float* ln_g = (const float*)d_in[2];
  const float* ln_b = (const float*)d_in[3];
  const float* w1 = (const float*)d_in[4];
  const float* b1 = (const float*)d_in[5];
  const float* w2 = (const float*)d_in[6];
  const float* b2 = (const float*)d_in[7];
  const float* w3 = (const float*)d_in[8];
  const float* b3 = (const float*)d_in[9];
  const float* cb = (const float*)d_in[10];
  const float* th0 = (const float*)d_in[11];
  const float* wh0 = (const float*)d_in[12];
  const float* wt0 = (const float*)d_in[13];
  const float* bt0 = (const float*)d_in[14];
  const float* th1 = (const float*)d_in[15];
  const float* wh1 = (const float*)d_in[16];
  const float* wt1 = (const float*)d_in[17];
  const float* bt1 = (const float*)d_in[18];
  float* out = (float*)d_out;

  char* ws = (char*)d_ws;
  size_t off = 0;
  auto alloc = [&](size_t bytes) -> void* {
    void* p = ws + off; off += (bytes + 255) & ~(size_t)255; return p;
  };
  int* flags = (int*)alloc(2*sizeof(int));
  int* hist  = (int*)alloc((size_t)B_*NIDS_*4);
  int* offs  = (int*)alloc((size_t)B_*NIDS_*4);
  int* bidx  = (int*)alloc((size_t)T_*4);
  int* split = (int*)alloc((size_t)T_*4);
  float* mskf = (float*)alloc((size_t)T_*4);
  float* mskg = (float*)alloc((size_t)T_*4);
  float* cbp = (float*)alloc((size_t)128*128*4);
  u16* thT0 = (u16*)alloc((size_t)D_*D_*2);
  u16* thT1 = (u16*)alloc((size_t)D_*D_*2);
  u16* wtwh0 = (u16*)alloc((size_t)512*D_*2);
  u16* wtwh1 = (u16*)alloc((size_t)512*D_*2);
  // BIG0: FFN intermediates P|Q (fp32, T*128 each)
  char* regA = (char*)alloc((size_t)T_*512*2);
  // BIG1..BIG3
  u16* xmh = (u16*)alloc((size_t)T_*D_*2);
  char* regC = (char*)alloc((size_t)T_*D_*2);   // xkh | dmb
  u16* xb1 = (u16*)alloc((size_t)T_*D_*2);
  if (off > ws_size) return;  // insufficient workspace: leave poison (visible failure)

  float* P = (float*)regA;
  float* Q = P + (size_t)T_*DD_;
  u16* xkh = (u16*)regC;
  u16* dmb = xkh + (size_t)T_*DD_;
  float* xn = out;            // d_out holds xn until the final k_fuse<1> scatter

  hipMemsetAsync(flags, 0, 2*sizeof(int), stream);
  hipMemsetAsync(hist, 0, (size_t)B_*NIDS_*4, stream);

  k_mask_detect<<<64, 256, 0, stream>>>((const unsigned int*)msk, flags);
  k_mask_convert<<<T_/256, 256, 0, stream>>>(msk, flags, mskf);

  k_ln<<<T_/4, 256, 0, stream>>>(x, ln_g, ln_b, xn);

  k_cbpad<<<128, 128, 0, stream>>>(cb, cbp);
  k_wt<<<256, 256, 0, stream>>>(th0, thT0);
  k_wt<<<256, 256, 0, stream>>>(th1, thT1);
  k_wt2<<<512, 256, 0, stream>>>(wt0, wh0, wtwh0);
  k_wt2<<<512, 256, 0, stream>>>(wt1, wh1, wtwh1);

  // FFN (exact fp32 — same per-output fmaf chains; bins bit-identical)
  k_gemm2<D_><<<T_/128, 256, 0, stream>>>(xn, w1, b1, P);
  k_gemm2<H_><<<T_/128, 256, 0, stream>>>(P, w2, b2, Q);
  k_gemm2<H_><<<T_/128, 256, 0, stream>>>(Q, w3, b3, P);

  // LSH
  k_mulmax<<<T_/128, 256, 0, stream>>>(P, cbp, mskf, bidx);
  k_hist<<<T_/256, 256, 0, stream>>>(bidx, hist);
  k_prefix<<<1, 64, 0, stream>>>(hist, offs);
  k_binsort<<<B_*NIDS_, 64, 0, stream>>>(bidx, offs, hist, split);

  k_gather<<<T_/4, 256, 0, stream>>>(xn, P, mskf, split, xmh, xkh, mskg);
  k_dm<<<GT_, 256, 0, stream>>>(xkh, mskg, dmb);

  // layer 0 (two-phase fused kernel; 1D grid with XCD swizzle)
  k_fuse<0><<<2*GT_, 256, 0, stream>>>(dmb, thT0, wtwh0, xmh, bt0, nullptr, xb1, nullptr);
  // layer 1 (writes final output scattered via split)
  k_fuse<1><<<2*GT_, 256, 0, stream>>>(dmb, thT1, wtwh1, xb1, bt1, split, nullptr, out);
}